// Round 3
// baseline (256.688 us; speedup 1.0000x reference)
//
#include <hip/hip_runtime.h>
#include <stdint.h>

#define NROWS 8192   // B*S
#define HDIM  128
#define KSUB  8
#define NC    4096
#define DSUB  16
#define OUTD  6

// ws layout:
//   xk     : [KSUB][NROWS][DSUB] fp32  (4 MiB)  -- k-major so argmin row loads coalesce
//   minpack: NROWS*KSUB u64            (512 KiB)
//   cnorm  : KSUB*NC fp32              (128 KiB)

// ---------------- Kernel 1: MLP + centroid norms + minpack init ----------------
__global__ __launch_bounds__(256) void mlp_kernel(
    const float* __restrict__ z, const float* __restrict__ W1, const float* __restrict__ b1,
    const float* __restrict__ W2, const float* __restrict__ b2,
    const float* __restrict__ centroids,
    float* __restrict__ xk, float* __restrict__ cnorm,
    unsigned long long* __restrict__ minpack)
{
    __shared__ float h1s[32 * HDIM];    // 16 KiB
    __shared__ float w2s[HDIM * HDIM];  // 64 KiB
    const int t = threadIdx.x;
    const int row0 = blockIdx.x * 32;

    // init minpack: 256 blocks * 256 threads == NROWS*KSUB
    minpack[blockIdx.x * 256 + t] = 0xFFFFFFFFFFFFFFFFull;

    // centroid norms (blocks 0..127 cover KSUB*NC = 32768 centroids)
    if (blockIdx.x < (KSUB * NC) / 256) {
        const int g = blockIdx.x * 256 + t;
        const float4* cp = (const float4*)&centroids[(size_t)g * DSUB];
        float nn = 0.f;
        #pragma unroll
        for (int q = 0; q < 4; ++q) {
            const float4 v = cp[q];
            nn = fmaf(v.x, v.x, nn); nn = fmaf(v.y, v.y, nn);
            nn = fmaf(v.z, v.z, nn); nn = fmaf(v.w, v.w, nn);
        }
        cnorm[g] = nn;
    }

    // stage W2 (16384 floats, coalesced)
    {
        const float4* g4 = (const float4*)W2;
        float4* s4 = (float4*)w2s;
        #pragma unroll
        for (int q = 0; q < 16; ++q) s4[t + q * 256] = g4[t + q * 256];
    }

    // phase A: h1 = relu(z @ W1 + b1) into LDS (32x128)
    #pragma unroll
    for (int e = 0; e < 16; ++e) {
        const int idx = e * 256 + t;
        const int r = idx >> 7, j = idx & 127;
        const int n = row0 + r;
        float acc = b1[j];
        acc = fmaf(z[n * 3 + 0], W1[0 * HDIM + j], acc);
        acc = fmaf(z[n * 3 + 1], W1[1 * HDIM + j], acc);
        acc = fmaf(z[n * 3 + 2], W1[2 * HDIM + j], acc);
        h1s[idx] = fmaxf(acc, 0.f);
    }
    __syncthreads();

    // phase B: 4 rows x 4 cols per thread
    const int c4 = (t & 31) * 4;   // col base
    const int r4 = (t >> 5) * 4;   // row base
    float acc[4][4];
    #pragma unroll
    for (int a = 0; a < 4; ++a)
        #pragma unroll
        for (int b = 0; b < 4; ++b) acc[a][b] = 0.f;

    for (int k4 = 0; k4 < HDIM; k4 += 4) {
        float hh[4][4], ww[4][4];
        #pragma unroll
        for (int q = 0; q < 4; ++q) {
            const float4 v = *(const float4*)&h1s[(r4 + q) * HDIM + k4];
            hh[q][0] = v.x; hh[q][1] = v.y; hh[q][2] = v.z; hh[q][3] = v.w;
        }
        #pragma unroll
        for (int p = 0; p < 4; ++p) {
            const float4 v = *(const float4*)&w2s[(k4 + p) * HDIM + c4];
            ww[p][0] = v.x; ww[p][1] = v.y; ww[p][2] = v.z; ww[p][3] = v.w;
        }
        #pragma unroll
        for (int q = 0; q < 4; ++q)
            #pragma unroll
            for (int p = 0; p < 4; ++p) {
                acc[q][0] = fmaf(hh[q][p], ww[p][0], acc[q][0]);
                acc[q][1] = fmaf(hh[q][p], ww[p][1], acc[q][1]);
                acc[q][2] = fmaf(hh[q][p], ww[p][2], acc[q][2]);
                acc[q][3] = fmaf(hh[q][p], ww[p][3], acc[q][3]);
            }
    }

    const float4 bb = *(const float4*)&b2[c4];
    const int kk = c4 >> 4;        // subspace of these 4 cols
    const int dd = c4 & 15;        // offset within subspace
    #pragma unroll
    for (int q = 0; q < 4; ++q) {
        float4 o;
        o.x = fmaxf(acc[q][0] + bb.x, 0.f);
        o.y = fmaxf(acc[q][1] + bb.y, 0.f);
        o.z = fmaxf(acc[q][2] + bb.z, 0.f);
        o.w = fmaxf(acc[q][3] + bb.w, 0.f);
        *(float4*)&xk[((size_t)kk * NROWS + (row0 + r4 + q)) * DSUB + dd] = o;
    }
}

// ---------------- Kernel 2: per-(row,k) argmin over centroids ----------------
// NO LDS: centroid values are wave-uniform -> compiler scalarizes to s_load,
// inner loop is pure v_fma(vgpr, sgpr, vgpr). 8 rows/thread = 8 indep FMA chains.
// grid (4 rowblocks, 8 k, 32 c-splits) = 1024 blocks, 128 centroids each.
#define RPT 8
#define CPB 128

__global__ __launch_bounds__(256) void argmin_kernel(
    const float* __restrict__ xk, const float* __restrict__ centroids,
    const float* __restrict__ cnorm, unsigned long long* __restrict__ minpack)
{
    const int t = threadIdx.x;
    const int rb = blockIdx.x;   // 0..3
    const int k  = blockIdx.y;   // 0..7
    const int cz = blockIdx.z;   // 0..31
    const int row0 = rb * 2048 + t;
    const int cb = cz * CPB;

    // load 8 row-fragments, pre-scaled by -2 (exact pow2 scale)
    float xr[RPT][DSUB];
    #pragma unroll
    for (int rr = 0; rr < RPT; ++rr) {
        const float* xp = &xk[((size_t)k * NROWS + row0 + rr * 256) * DSUB];
        #pragma unroll
        for (int q = 0; q < DSUB; q += 4) {
            const float4 v = *(const float4*)&xp[q];
            xr[rr][q + 0] = -2.f * v.x; xr[rr][q + 1] = -2.f * v.y;
            xr[rr][q + 2] = -2.f * v.z; xr[rr][q + 3] = -2.f * v.w;
        }
    }

    float mv[RPT]; int mi[RPT];
    #pragma unroll
    for (int rr = 0; rr < RPT; ++rr) { mv[rr] = 1e30f; mi[rr] = 0; }

    const float* cp  = &centroids[((size_t)k * NC + cb) * DSUB];
    const float* cnp = &cnorm[k * NC + cb];

    #pragma unroll 2
    for (int cc = 0; cc < CPB; ++cc) {
        float c[DSUB];
        #pragma unroll
        for (int d = 0; d < DSUB; ++d) c[d] = cp[cc * DSUB + d];  // uniform -> s_load
        const float nrm = cnp[cc];                                 // uniform -> s_load
        #pragma unroll
        for (int rr = 0; rr < RPT; ++rr) {
            float s = fmaf(xr[rr][0], c[0], nrm);   // s = nrm - 2*dot
            s = fmaf(xr[rr][1],  c[1],  s);
            s = fmaf(xr[rr][2],  c[2],  s);
            s = fmaf(xr[rr][3],  c[3],  s);
            s = fmaf(xr[rr][4],  c[4],  s);
            s = fmaf(xr[rr][5],  c[5],  s);
            s = fmaf(xr[rr][6],  c[6],  s);
            s = fmaf(xr[rr][7],  c[7],  s);
            s = fmaf(xr[rr][8],  c[8],  s);
            s = fmaf(xr[rr][9],  c[9],  s);
            s = fmaf(xr[rr][10], c[10], s);
            s = fmaf(xr[rr][11], c[11], s);
            s = fmaf(xr[rr][12], c[12], s);
            s = fmaf(xr[rr][13], c[13], s);
            s = fmaf(xr[rr][14], c[14], s);
            s = fmaf(xr[rr][15], c[15], s);
            if (s < mv[rr]) { mv[rr] = s; mi[rr] = cb + cc; }  // strict < => lowest idx wins
        }
    }

    #pragma unroll
    for (int rr = 0; rr < RPT; ++rr) {
        unsigned u = __float_as_uint(mv[rr]);
        u = (u & 0x80000000u) ? ~u : (u | 0x80000000u);  // order-preserving float->uint
        atomicMin(&minpack[(size_t)(row0 + rr * 256) * KSUB + k],
                  ((unsigned long long)u << 32) | (unsigned)mi[rr]);
    }
}

// ---------------- Kernel 3: LUT gather + sum + bias -> llr ----------------
__global__ __launch_bounds__(256) void out_kernel(
    const float* __restrict__ centroids, const float* __restrict__ W3,
    const float* __restrict__ b3, const unsigned long long* __restrict__ minpack,
    float* __restrict__ out)
{
    const int gid = blockIdx.x * 256 + threadIdx.x;
    const int n = gid / OUTD;
    const int o = gid - n * OUTD;
    float acc = b3[o];
    #pragma unroll
    for (int k = 0; k < KSUB; ++k) {
        const int code = (int)(minpack[(size_t)n * KSUB + k] & 0xFFFFFFFFull);
        const float* cp = &centroids[((size_t)k * NC + code) * DSUB];
        const float* wp = &W3[(k * DSUB) * OUTD + o];
        #pragma unroll
        for (int d = 0; d < DSUB; ++d)
            acc = fmaf(cp[d], wp[d * OUTD], acc);
    }
    out[gid] = acc;
}

extern "C" void kernel_launch(void* const* d_in, const int* in_sizes, int n_in,
                              void* d_out, int out_size, void* d_ws, size_t ws_size,
                              hipStream_t stream)
{
    const float* z  = (const float*)d_in[0];
    const float* W1 = (const float*)d_in[1];
    const float* b1 = (const float*)d_in[2];
    const float* W2 = (const float*)d_in[3];
    const float* b2 = (const float*)d_in[4];
    const float* ce = (const float*)d_in[5];
    const float* W3 = (const float*)d_in[6];
    const float* b3 = (const float*)d_in[7];

    char* ws = (char*)d_ws;
    float* xk = (float*)ws;                                                   // 4 MiB
    unsigned long long* minpack = (unsigned long long*)(ws + (size_t)NROWS * HDIM * 4);  // +512 KiB
    float* cnorm = (float*)(ws + (size_t)NROWS * HDIM * 4 + (size_t)NROWS * KSUB * 8);   // +128 KiB

    hipLaunchKernelGGL(mlp_kernel, dim3(NROWS / 32), dim3(256), 0, stream,
                       z, W1, b1, W2, b2, ce, xk, cnorm, minpack);
    hipLaunchKernelGGL(argmin_kernel, dim3(4, 8, 32), dim3(256), 0, stream,
                       xk, ce, cnorm, minpack);
    hipLaunchKernelGGL(out_kernel, dim3((NROWS * OUTD) / 256), dim3(256), 0, stream,
                       ce, W3, b3, minpack, (float*)d_out);
}

// Round 4
// 240.314 us; speedup vs baseline: 1.0681x; 1.0681x over previous
//
#include <hip/hip_runtime.h>
#include <stdint.h>

#define NROWS 8192   // B*S
#define HDIM  128
#define KSUB  8
#define NC    4096
#define DSUB  16
#define OUTD  6

// ws layout:
//   xk     : [KSUB][NROWS][DSUB] fp32  (4 MiB)
//   minpack: NROWS*KSUB u64            (512 KiB)
//   cnorm  : KSUB*NC fp32              (128 KiB)

// ---------------- Kernel 1: MLP + centroid norms + minpack init ----------------
__global__ __launch_bounds__(256) void mlp_kernel(
    const float* __restrict__ z, const float* __restrict__ W1, const float* __restrict__ b1,
    const float* __restrict__ W2, const float* __restrict__ b2,
    const float* __restrict__ centroids,
    float* __restrict__ xk, float* __restrict__ cnorm,
    unsigned long long* __restrict__ minpack)
{
    __shared__ float h1s[32 * HDIM];    // 16 KiB
    __shared__ float w2s[HDIM * HDIM];  // 64 KiB
    const int t = threadIdx.x;
    const int row0 = blockIdx.x * 32;

    // init minpack: 256 blocks * 256 threads == NROWS*KSUB
    minpack[blockIdx.x * 256 + t] = 0xFFFFFFFFFFFFFFFFull;

    // centroid norms (blocks 0..127 cover KSUB*NC = 32768 centroids)
    if (blockIdx.x < (KSUB * NC) / 256) {
        const int g = blockIdx.x * 256 + t;
        const float4* cp = (const float4*)&centroids[(size_t)g * DSUB];
        float nn = 0.f;
        #pragma unroll
        for (int q = 0; q < 4; ++q) {
            const float4 v = cp[q];
            nn = fmaf(v.x, v.x, nn); nn = fmaf(v.y, v.y, nn);
            nn = fmaf(v.z, v.z, nn); nn = fmaf(v.w, v.w, nn);
        }
        cnorm[g] = nn;
    }

    // stage W2 (coalesced)
    {
        const float4* g4 = (const float4*)W2;
        float4* s4 = (float4*)w2s;
        #pragma unroll
        for (int q = 0; q < 16; ++q) s4[t + q * 256] = g4[t + q * 256];
    }

    // phase A: h1 = relu(z @ W1 + b1) into LDS (32x128)
    #pragma unroll
    for (int e = 0; e < 16; ++e) {
        const int idx = e * 256 + t;
        const int r = idx >> 7, j = idx & 127;
        const int n = row0 + r;
        float acc = b1[j];
        acc = fmaf(z[n * 3 + 0], W1[0 * HDIM + j], acc);
        acc = fmaf(z[n * 3 + 1], W1[1 * HDIM + j], acc);
        acc = fmaf(z[n * 3 + 2], W1[2 * HDIM + j], acc);
        h1s[idx] = fmaxf(acc, 0.f);
    }
    __syncthreads();

    // phase B: 4 rows x 4 cols per thread
    const int c4 = (t & 31) * 4;
    const int r4 = (t >> 5) * 4;
    float acc[4][4];
    #pragma unroll
    for (int a = 0; a < 4; ++a)
        #pragma unroll
        for (int b = 0; b < 4; ++b) acc[a][b] = 0.f;

    for (int k4 = 0; k4 < HDIM; k4 += 4) {
        float hh[4][4], ww[4][4];
        #pragma unroll
        for (int q = 0; q < 4; ++q) {
            const float4 v = *(const float4*)&h1s[(r4 + q) * HDIM + k4];
            hh[q][0] = v.x; hh[q][1] = v.y; hh[q][2] = v.z; hh[q][3] = v.w;
        }
        #pragma unroll
        for (int p = 0; p < 4; ++p) {
            const float4 v = *(const float4*)&w2s[(k4 + p) * HDIM + c4];
            ww[p][0] = v.x; ww[p][1] = v.y; ww[p][2] = v.z; ww[p][3] = v.w;
        }
        #pragma unroll
        for (int q = 0; q < 4; ++q)
            #pragma unroll
            for (int p = 0; p < 4; ++p) {
                acc[q][0] = fmaf(hh[q][p], ww[p][0], acc[q][0]);
                acc[q][1] = fmaf(hh[q][p], ww[p][1], acc[q][1]);
                acc[q][2] = fmaf(hh[q][p], ww[p][2], acc[q][2]);
                acc[q][3] = fmaf(hh[q][p], ww[p][3], acc[q][3]);
            }
    }

    const float4 bb = *(const float4*)&b2[c4];
    const int kk = c4 >> 4;
    const int dd = c4 & 15;
    #pragma unroll
    for (int q = 0; q < 4; ++q) {
        float4 o;
        o.x = fmaxf(acc[q][0] + bb.x, 0.f);
        o.y = fmaxf(acc[q][1] + bb.y, 0.f);
        o.z = fmaxf(acc[q][2] + bb.z, 0.f);
        o.w = fmaxf(acc[q][3] + bb.w, 0.f);
        *(float4*)&xk[((size_t)kk * NROWS + (row0 + r4 + q)) * DSUB + dd] = o;
    }
}

// ---------------- Kernel 2: per-(row,k) argmin over centroids ----------------
// LDS-broadcast centroids (round-2 structure) + 8 rows/thread so the VALU,
// not the shared per-CU LDS pipe, is the limiter:
//   per wave-centroid: LDS = 4x ds_read_b128 + 1x b32 ~ 54 cyc (1 pipe/CU)
//   VALU = 8 rows x 19 ops x 2 cyc = 304 cyc (per SIMD) -> LDS pipe ~71% loaded.
// grid (4 rowblocks, 8 k, 32 c-splits) = 1024 blocks; one 128-centroid chunk each.
#define RPT 8
#define CPB 128

__global__ __launch_bounds__(256) void argmin_kernel(
    const float* __restrict__ xk, const float* __restrict__ centroids,
    const float* __restrict__ cnorm, unsigned long long* __restrict__ minpack)
{
    __shared__ float cs[CPB * DSUB];  // 8 KiB
    __shared__ float cn[CPB];         // 512 B
    const int t = threadIdx.x;
    const int rb = blockIdx.x;   // 0..3
    const int k  = blockIdx.y;   // 0..7
    const int cz = blockIdx.z;   // 0..31
    const int row0 = rb * 2048 + t;
    const int cb = cz * CPB;

    // stage 128 centroids (2048 floats) + norms, coalesced
    {
        const float4* gp = (const float4*)&centroids[((size_t)k * NC + cb) * DSUB];
        float4* sp = (float4*)cs;
        sp[t] = gp[t];
        sp[t + 256] = gp[t + 256];
        if (t < CPB) cn[t] = cnorm[k * NC + cb + t];
    }

    // load 8 row-fragments, pre-scaled by -2 (exact pow2 scale)
    float xr[RPT][DSUB];
    #pragma unroll
    for (int rr = 0; rr < RPT; ++rr) {
        const float* xp = &xk[((size_t)k * NROWS + row0 + rr * 256) * DSUB];
        #pragma unroll
        for (int q = 0; q < DSUB; q += 4) {
            const float4 v = *(const float4*)&xp[q];
            xr[rr][q + 0] = -2.f * v.x; xr[rr][q + 1] = -2.f * v.y;
            xr[rr][q + 2] = -2.f * v.z; xr[rr][q + 3] = -2.f * v.w;
        }
    }

    __syncthreads();

    float mv[RPT]; int mi[RPT];
    #pragma unroll
    for (int rr = 0; rr < RPT; ++rr) { mv[rr] = 1e30f; mi[rr] = 0; }

    #pragma unroll 2
    for (int cc = 0; cc < CPB; ++cc) {
        const float4 c0 = *(const float4*)&cs[cc * DSUB + 0];
        const float4 c1 = *(const float4*)&cs[cc * DSUB + 4];
        const float4 c2 = *(const float4*)&cs[cc * DSUB + 8];
        const float4 c3 = *(const float4*)&cs[cc * DSUB + 12];
        const float nrm = cn[cc];
        #pragma unroll
        for (int rr = 0; rr < RPT; ++rr) {
            float s = fmaf(xr[rr][0], c0.x, nrm);   // s = nrm - 2*dot
            s = fmaf(xr[rr][1],  c0.y, s);
            s = fmaf(xr[rr][2],  c0.z, s);
            s = fmaf(xr[rr][3],  c0.w, s);
            s = fmaf(xr[rr][4],  c1.x, s);
            s = fmaf(xr[rr][5],  c1.y, s);
            s = fmaf(xr[rr][6],  c1.z, s);
            s = fmaf(xr[rr][7],  c1.w, s);
            s = fmaf(xr[rr][8],  c2.x, s);
            s = fmaf(xr[rr][9],  c2.y, s);
            s = fmaf(xr[rr][10], c2.z, s);
            s = fmaf(xr[rr][11], c2.w, s);
            s = fmaf(xr[rr][12], c3.x, s);
            s = fmaf(xr[rr][13], c3.y, s);
            s = fmaf(xr[rr][14], c3.z, s);
            s = fmaf(xr[rr][15], c3.w, s);
            if (s < mv[rr]) { mv[rr] = s; mi[rr] = cb + cc; }  // strict < => lowest idx wins
        }
    }

    #pragma unroll
    for (int rr = 0; rr < RPT; ++rr) {
        unsigned u = __float_as_uint(mv[rr]);
        u = (u & 0x80000000u) ? ~u : (u | 0x80000000u);  // order-preserving float->uint
        atomicMin(&minpack[(size_t)(row0 + rr * 256) * KSUB + k],
                  ((unsigned long long)u << 32) | (unsigned)mi[rr]);
    }
}

// ---------------- Kernel 3: LUT gather + sum + bias -> llr ----------------
__global__ __launch_bounds__(256) void out_kernel(
    const float* __restrict__ centroids, const float* __restrict__ W3,
    const float* __restrict__ b3, const unsigned long long* __restrict__ minpack,
    float* __restrict__ out)
{
    const int gid = blockIdx.x * 256 + threadIdx.x;
    const int n = gid / OUTD;
    const int o = gid - n * OUTD;
    float acc = b3[o];
    #pragma unroll
    for (int k = 0; k < KSUB; ++k) {
        const int code = (int)(minpack[(size_t)n * KSUB + k] & 0xFFFFFFFFull);
        const float* cp = &centroids[((size_t)k * NC + code) * DSUB];
        const float* wp = &W3[(k * DSUB) * OUTD + o];
        #pragma unroll
        for (int d = 0; d < DSUB; ++d)
            acc = fmaf(cp[d], wp[d * OUTD], acc);
    }
    out[gid] = acc;
}

extern "C" void kernel_launch(void* const* d_in, const int* in_sizes, int n_in,
                              void* d_out, int out_size, void* d_ws, size_t ws_size,
                              hipStream_t stream)
{
    const float* z  = (const float*)d_in[0];
    const float* W1 = (const float*)d_in[1];
    const float* b1 = (const float*)d_in[2];
    const float* W2 = (const float*)d_in[3];
    const float* b2 = (const float*)d_in[4];
    const float* ce = (const float*)d_in[5];
    const float* W3 = (const float*)d_in[6];
    const float* b3 = (const float*)d_in[7];

    char* ws = (char*)d_ws;
    float* xk = (float*)ws;                                                   // 4 MiB
    unsigned long long* minpack = (unsigned long long*)(ws + (size_t)NROWS * HDIM * 4);  // +512 KiB
    float* cnorm = (float*)(ws + (size_t)NROWS * HDIM * 4 + (size_t)NROWS * KSUB * 8);   // +128 KiB

    hipLaunchKernelGGL(mlp_kernel, dim3(NROWS / 32), dim3(256), 0, stream,
                       z, W1, b1, W2, b2, ce, xk, cnorm, minpack);
    hipLaunchKernelGGL(argmin_kernel, dim3(4, 8, 32), dim3(256), 0, stream,
                       xk, ce, cnorm, minpack);
    hipLaunchKernelGGL(out_kernel, dim3((NROWS * OUTD) / 256), dim3(256), 0, stream,
                       ce, W3, b3, minpack, (float*)d_out);
}

// Round 5
// 220.344 us; speedup vs baseline: 1.1649x; 1.0906x over previous
//
#include <hip/hip_runtime.h>
#include <stdint.h>

#define NROWS 8192   // B*S
#define HDIM  128
#define KSUB  8
#define NC    4096
#define DSUB  16
#define OUTD  6

// ws layout:
//   xk     : [KSUB][NROWS][DSUB] fp32  (4 MiB)
//   minpack: NROWS*KSUB u64            (512 KiB)
//   cnorm  : KSUB*NC fp32              (128 KiB)

// ---------------- Kernel 1: MLP + centroid norms + minpack init ----------------
__global__ __launch_bounds__(256) void mlp_kernel(
    const float* __restrict__ z, const float* __restrict__ W1, const float* __restrict__ b1,
    const float* __restrict__ W2, const float* __restrict__ b2,
    const float* __restrict__ centroids,
    float* __restrict__ xk, float* __restrict__ cnorm,
    unsigned long long* __restrict__ minpack)
{
    __shared__ float h1s[32 * HDIM];    // 16 KiB
    __shared__ float w2s[HDIM * HDIM];  // 64 KiB
    const int t = threadIdx.x;
    const int row0 = blockIdx.x * 32;

    // init minpack: 256 blocks * 256 threads == NROWS*KSUB
    minpack[blockIdx.x * 256 + t] = 0xFFFFFFFFFFFFFFFFull;

    // centroid norms (blocks 0..127 cover KSUB*NC = 32768 centroids)
    if (blockIdx.x < (KSUB * NC) / 256) {
        const int g = blockIdx.x * 256 + t;
        const float4* cp = (const float4*)&centroids[(size_t)g * DSUB];
        float nn = 0.f;
        #pragma unroll
        for (int q = 0; q < 4; ++q) {
            const float4 v = cp[q];
            nn = fmaf(v.x, v.x, nn); nn = fmaf(v.y, v.y, nn);
            nn = fmaf(v.z, v.z, nn); nn = fmaf(v.w, v.w, nn);
        }
        cnorm[g] = nn;
    }

    // stage W2 (coalesced)
    {
        const float4* g4 = (const float4*)W2;
        float4* s4 = (float4*)w2s;
        #pragma unroll
        for (int q = 0; q < 16; ++q) s4[t + q * 256] = g4[t + q * 256];
    }

    // phase A: h1 = relu(z @ W1 + b1) into LDS (32x128)
    #pragma unroll
    for (int e = 0; e < 16; ++e) {
        const int idx = e * 256 + t;
        const int r = idx >> 7, j = idx & 127;
        const int n = row0 + r;
        float acc = b1[j];
        acc = fmaf(z[n * 3 + 0], W1[0 * HDIM + j], acc);
        acc = fmaf(z[n * 3 + 1], W1[1 * HDIM + j], acc);
        acc = fmaf(z[n * 3 + 2], W1[2 * HDIM + j], acc);
        h1s[idx] = fmaxf(acc, 0.f);
    }
    __syncthreads();

    // phase B: 4 rows x 4 cols per thread
    const int c4 = (t & 31) * 4;
    const int r4 = (t >> 5) * 4;
    float acc[4][4];
    #pragma unroll
    for (int a = 0; a < 4; ++a)
        #pragma unroll
        for (int b = 0; b < 4; ++b) acc[a][b] = 0.f;

    for (int k4 = 0; k4 < HDIM; k4 += 4) {
        float hh[4][4], ww[4][4];
        #pragma unroll
        for (int q = 0; q < 4; ++q) {
            const float4 v = *(const float4*)&h1s[(r4 + q) * HDIM + k4];
            hh[q][0] = v.x; hh[q][1] = v.y; hh[q][2] = v.z; hh[q][3] = v.w;
        }
        #pragma unroll
        for (int p = 0; p < 4; ++p) {
            const float4 v = *(const float4*)&w2s[(k4 + p) * HDIM + c4];
            ww[p][0] = v.x; ww[p][1] = v.y; ww[p][2] = v.z; ww[p][3] = v.w;
        }
        #pragma unroll
        for (int q = 0; q < 4; ++q)
            #pragma unroll
            for (int p = 0; p < 4; ++p) {
                acc[q][0] = fmaf(hh[q][p], ww[p][0], acc[q][0]);
                acc[q][1] = fmaf(hh[q][p], ww[p][1], acc[q][1]);
                acc[q][2] = fmaf(hh[q][p], ww[p][2], acc[q][2]);
                acc[q][3] = fmaf(hh[q][p], ww[p][3], acc[q][3]);
            }
    }

    const float4 bb = *(const float4*)&b2[c4];
    const int kk = c4 >> 4;
    const int dd = c4 & 15;
    #pragma unroll
    for (int q = 0; q < 4; ++q) {
        float4 o;
        o.x = fmaxf(acc[q][0] + bb.x, 0.f);
        o.y = fmaxf(acc[q][1] + bb.y, 0.f);
        o.z = fmaxf(acc[q][2] + bb.z, 0.f);
        o.w = fmaxf(acc[q][3] + bb.w, 0.f);
        *(float4*)&xk[((size_t)kk * NROWS + (row0 + r4 + q)) * DSUB + dd] = o;
    }
}

// ---------------- Kernel 2: per-(row,k) argmin over centroids ----------------
// LDS-broadcast centroids + 8 resident rows/thread. __launch_bounds__(256,2)
// raises the VGPR cap to 256 so xr[8][16] (128 regs) actually stays in
// registers -- rounds 2-4 showed the compiler re-loading it from global when
// capped at ~84 VGPRs (VGPR_Count is the tell: must be >=170 here).
// grid (4 rowblocks, 8 k, 32 c-splits) = 1024 blocks; one 128-centroid chunk each.
#define RPT 8
#define CPB 128

__global__ __launch_bounds__(256, 2) void argmin_kernel(
    const float* __restrict__ xk, const float* __restrict__ centroids,
    const float* __restrict__ cnorm, unsigned long long* __restrict__ minpack)
{
    __shared__ float cs[CPB * DSUB];  // 8 KiB
    __shared__ float cn[CPB];         // 512 B
    const int t = threadIdx.x;
    const int rb = blockIdx.x;   // 0..3
    const int k  = blockIdx.y;   // 0..7
    const int cz = blockIdx.z;   // 0..31
    const int row0 = rb * 2048 + t;
    const int cb = cz * CPB;

    // stage 128 centroids (2048 floats) + norms, coalesced
    {
        const float4* gp = (const float4*)&centroids[((size_t)k * NC + cb) * DSUB];
        float4* sp = (float4*)cs;
        sp[t] = gp[t];
        sp[t + 256] = gp[t + 256];
        if (t < CPB) cn[t] = cnorm[k * NC + cb + t];
    }

    // load 8 row-fragments, pre-scaled by -2 (exact pow2 scale)
    float xr[RPT][DSUB];
    #pragma unroll
    for (int rr = 0; rr < RPT; ++rr) {
        const float* xp = &xk[((size_t)k * NROWS + row0 + rr * 256) * DSUB];
        #pragma unroll
        for (int q = 0; q < DSUB; q += 4) {
            const float4 v = *(const float4*)&xp[q];
            xr[rr][q + 0] = -2.f * v.x; xr[rr][q + 1] = -2.f * v.y;
            xr[rr][q + 2] = -2.f * v.z; xr[rr][q + 3] = -2.f * v.w;
        }
    }

    __syncthreads();

    float mv[RPT]; int mi[RPT];
    #pragma unroll
    for (int rr = 0; rr < RPT; ++rr) { mv[rr] = 1e30f; mi[rr] = 0; }

    #pragma unroll 2
    for (int cc = 0; cc < CPB; ++cc) {
        const float4 c0 = *(const float4*)&cs[cc * DSUB + 0];
        const float4 c1 = *(const float4*)&cs[cc * DSUB + 4];
        const float4 c2 = *(const float4*)&cs[cc * DSUB + 8];
        const float4 c3 = *(const float4*)&cs[cc * DSUB + 12];
        const float nrm = cn[cc];
        #pragma unroll
        for (int rr = 0; rr < RPT; ++rr) {
            float s = fmaf(xr[rr][0], c0.x, nrm);   // s = nrm - 2*dot
            s = fmaf(xr[rr][1],  c0.y, s);
            s = fmaf(xr[rr][2],  c0.z, s);
            s = fmaf(xr[rr][3],  c0.w, s);
            s = fmaf(xr[rr][4],  c1.x, s);
            s = fmaf(xr[rr][5],  c1.y, s);
            s = fmaf(xr[rr][6],  c1.z, s);
            s = fmaf(xr[rr][7],  c1.w, s);
            s = fmaf(xr[rr][8],  c2.x, s);
            s = fmaf(xr[rr][9],  c2.y, s);
            s = fmaf(xr[rr][10], c2.z, s);
            s = fmaf(xr[rr][11], c2.w, s);
            s = fmaf(xr[rr][12], c3.x, s);
            s = fmaf(xr[rr][13], c3.y, s);
            s = fmaf(xr[rr][14], c3.z, s);
            s = fmaf(xr[rr][15], c3.w, s);
            if (s < mv[rr]) { mv[rr] = s; mi[rr] = cb + cc; }  // strict < => lowest idx wins
        }
    }

    #pragma unroll
    for (int rr = 0; rr < RPT; ++rr) {
        unsigned u = __float_as_uint(mv[rr]);
        u = (u & 0x80000000u) ? ~u : (u | 0x80000000u);  // order-preserving float->uint
        atomicMin(&minpack[(size_t)(row0 + rr * 256) * KSUB + k],
                  ((unsigned long long)u << 32) | (unsigned)mi[rr]);
    }
}

// ---------------- Kernel 3: LUT gather + sum + bias -> llr ----------------
__global__ __launch_bounds__(256) void out_kernel(
    const float* __restrict__ centroids, const float* __restrict__ W3,
    const float* __restrict__ b3, const unsigned long long* __restrict__ minpack,
    float* __restrict__ out)
{
    const int gid = blockIdx.x * 256 + threadIdx.x;
    const int n = gid / OUTD;
    const int o = gid - n * OUTD;
    float acc = b3[o];
    #pragma unroll
    for (int k = 0; k < KSUB; ++k) {
        const int code = (int)(minpack[(size_t)n * KSUB + k] & 0xFFFFFFFFull);
        const float* cp = &centroids[((size_t)k * NC + code) * DSUB];
        const float* wp = &W3[(k * DSUB) * OUTD + o];
        #pragma unroll
        for (int d = 0; d < DSUB; ++d)
            acc = fmaf(cp[d], wp[d * OUTD], acc);
    }
    out[gid] = acc;
}

extern "C" void kernel_launch(void* const* d_in, const int* in_sizes, int n_in,
                              void* d_out, int out_size, void* d_ws, size_t ws_size,
                              hipStream_t stream)
{
    const float* z  = (const float*)d_in[0];
    const float* W1 = (const float*)d_in[1];
    const float* b1 = (const float*)d_in[2];
    const float* W2 = (const float*)d_in[3];
    const float* b2 = (const float*)d_in[4];
    const float* ce = (const float*)d_in[5];
    const float* W3 = (const float*)d_in[6];
    const float* b3 = (const float*)d_in[7];

    char* ws = (char*)d_ws;
    float* xk = (float*)ws;                                                   // 4 MiB
    unsigned long long* minpack = (unsigned long long*)(ws + (size_t)NROWS * HDIM * 4);  // +512 KiB
    float* cnorm = (float*)(ws + (size_t)NROWS * HDIM * 4 + (size_t)NROWS * KSUB * 8);   // +128 KiB

    hipLaunchKernelGGL(mlp_kernel, dim3(NROWS / 32), dim3(256), 0, stream,
                       z, W1, b1, W2, b2, ce, xk, cnorm, minpack);
    hipLaunchKernelGGL(argmin_kernel, dim3(4, 8, 32), dim3(256), 0, stream,
                       xk, ce, cnorm, minpack);
    hipLaunchKernelGGL(out_kernel, dim3((NROWS * OUTD) / 256), dim3(256), 0, stream,
                       ce, W3, b3, minpack, (float*)d_out);
}

// Round 6
// 208.567 us; speedup vs baseline: 1.2307x; 1.0565x over previous
//
#include <hip/hip_runtime.h>
#include <stdint.h>

#define NROWS 8192   // B*S
#define HDIM  128
#define KSUB  8
#define NC    4096
#define DSUB  16
#define OUTD  6

#define FB_TAU 4e-3f          // fallback margin; >> worst-case split-fp16 error (~7e-4)
#define DOTSCALE (-2.0f / 4096.0f)  // undo x*256, c*16 scaling; exact pow2

typedef _Float16 f16x8 __attribute__((ext_vector_type(8)));
typedef float    f32x4 __attribute__((ext_vector_type(4)));

// ws layout (bytes):
#define XK_OFF 0u            // xk:    [KSUB][NROWS][DSUB] fp32, 4 MiB
#define CN_OFF 4194304u      // cnorm: [KSUB][NC] fp32, 128 KiB
#define B1_OFF 4325376u      // B1:    [KSUB][256 tiles][64 lanes] f16x8, 2 MiB
#define B2_OFF 6422528u      // B2:    same, swapped halves, 2 MiB
#define CO_OFF 8519680u      // codes: [NROWS][KSUB] int, 256 KiB
#define MG_OFF 8781824u      // margin:[NROWS][KSUB] fp32, 256 KiB

// ---------------- Kernel 0: build fp16 hi/lo centroid B-fragments ----------------
// entry e = (k, tile, lane). B1 lane quad<2 -> hi, quad>=2 -> lo; B2 swapped.
// k' semantics: k' 0-15 = hi dims 0-15 ; k' 16-31 = lo dims 0-15 (B1), reversed (B2).
__global__ __launch_bounds__(256) void bprep_kernel(
    const float* __restrict__ ce, f16x8* __restrict__ B1, f16x8* __restrict__ B2)
{
    const int e = blockIdx.x * 256 + threadIdx.x;   // 0..131071
    const int k    = e >> 14;
    const int tile = (e >> 6) & 255;
    const int lane = e & 63;
    const int col  = lane & 15;
    const int quad = lane >> 4;
    const int dims = (quad & 1) * 8;
    const int part = quad >> 1;                      // 0: hi half of K, 1: lo half
    const int n = tile * 16 + col;
    const float* cp = &ce[((size_t)k * NC + n) * DSUB + dims];
    f16x8 hi, lo;
    #pragma unroll
    for (int j = 0; j < 8; ++j) {
        const float s = cp[j] * 16.0f;               // pow2 scale keeps lo normal
        const _Float16 h = (_Float16)s;
        hi[j] = h;
        lo[j] = (_Float16)(s - (float)h);
    }
    B1[e] = part ? lo : hi;
    B2[e] = part ? hi : lo;
}

// ---------------- Kernel 1: MLP + centroid norms ----------------
__global__ __launch_bounds__(256) void mlp_kernel(
    const float* __restrict__ z, const float* __restrict__ W1, const float* __restrict__ b1,
    const float* __restrict__ W2, const float* __restrict__ b2,
    const float* __restrict__ centroids,
    float* __restrict__ xk, float* __restrict__ cnorm)
{
    __shared__ float h1s[32 * HDIM];    // 16 KiB
    __shared__ float w2s[HDIM * HDIM];  // 64 KiB
    const int t = threadIdx.x;
    const int row0 = blockIdx.x * 32;

    // centroid norms (blocks 0..127 cover KSUB*NC = 32768 centroids)
    if (blockIdx.x < (KSUB * NC) / 256) {
        const int g = blockIdx.x * 256 + t;
        const float4* cp = (const float4*)&centroids[(size_t)g * DSUB];
        float nn = 0.f;
        #pragma unroll
        for (int q = 0; q < 4; ++q) {
            const float4 v = cp[q];
            nn = fmaf(v.x, v.x, nn); nn = fmaf(v.y, v.y, nn);
            nn = fmaf(v.z, v.z, nn); nn = fmaf(v.w, v.w, nn);
        }
        cnorm[g] = nn;
    }

    // stage W2 (coalesced)
    {
        const float4* g4 = (const float4*)W2;
        float4* s4 = (float4*)w2s;
        #pragma unroll
        for (int q = 0; q < 16; ++q) s4[t + q * 256] = g4[t + q * 256];
    }

    // phase A: h1 = relu(z @ W1 + b1) into LDS (32x128)
    #pragma unroll
    for (int e = 0; e < 16; ++e) {
        const int idx = e * 256 + t;
        const int r = idx >> 7, j = idx & 127;
        const int n = row0 + r;
        float acc = b1[j];
        acc = fmaf(z[n * 3 + 0], W1[0 * HDIM + j], acc);
        acc = fmaf(z[n * 3 + 1], W1[1 * HDIM + j], acc);
        acc = fmaf(z[n * 3 + 2], W1[2 * HDIM + j], acc);
        h1s[idx] = fmaxf(acc, 0.f);
    }
    __syncthreads();

    // phase B: 4 rows x 4 cols per thread
    const int c4 = (t & 31) * 4;
    const int r4 = (t >> 5) * 4;
    float acc[4][4];
    #pragma unroll
    for (int a = 0; a < 4; ++a)
        #pragma unroll
        for (int b = 0; b < 4; ++b) acc[a][b] = 0.f;

    for (int k4 = 0; k4 < HDIM; k4 += 4) {
        float hh[4][4], ww[4][4];
        #pragma unroll
        for (int q = 0; q < 4; ++q) {
            const float4 v = *(const float4*)&h1s[(r4 + q) * HDIM + k4];
            hh[q][0] = v.x; hh[q][1] = v.y; hh[q][2] = v.z; hh[q][3] = v.w;
        }
        #pragma unroll
        for (int p = 0; p < 4; ++p) {
            const float4 v = *(const float4*)&w2s[(k4 + p) * HDIM + c4];
            ww[p][0] = v.x; ww[p][1] = v.y; ww[p][2] = v.z; ww[p][3] = v.w;
        }
        #pragma unroll
        for (int q = 0; q < 4; ++q)
            #pragma unroll
            for (int p = 0; p < 4; ++p) {
                acc[q][0] = fmaf(hh[q][p], ww[p][0], acc[q][0]);
                acc[q][1] = fmaf(hh[q][p], ww[p][1], acc[q][1]);
                acc[q][2] = fmaf(hh[q][p], ww[p][2], acc[q][2]);
                acc[q][3] = fmaf(hh[q][p], ww[p][3], acc[q][3]);
            }
    }

    const float4 bb = *(const float4*)&b2[c4];
    const int kk = c4 >> 4;
    const int dd = c4 & 15;
    #pragma unroll
    for (int q = 0; q < 4; ++q) {
        float4 o;
        o.x = fmaxf(acc[q][0] + bb.x, 0.f);
        o.y = fmaxf(acc[q][1] + bb.y, 0.f);
        o.z = fmaxf(acc[q][2] + bb.z, 0.f);
        o.w = fmaxf(acc[q][3] + bb.w, 0.f);
        *(float4*)&xk[((size_t)kk * NROWS + (row0 + r4 + q)) * DSUB + dd] = o;
    }
}

// ---------------- Kernel 2: MFMA argmin ----------------
// A = [xh | xl] (K=32), B1 = [ch | cl], B2 = [cl | ch]:
//   mfma(A,B1) + mfma(A,B2) = (xh+xl)·(ch+cl) exactly (fp32 accum).
// Each wave: 2 row-groups (32 rows) x one subspace k x all 4096 centroids
// (256 tiles of 16). Tracks (m1, m2, idx) per row; margin -> fallback flag.
// grid 512 blocks x 256 thr: k = bx>>6, rowblock = (bx&63)*4 + waveid.
__global__ __launch_bounds__(256) void argmin_kernel(
    const float* __restrict__ xk, const f16x8* __restrict__ B1,
    const f16x8* __restrict__ B2, const float* __restrict__ cnorm,
    int* __restrict__ codes, float* __restrict__ margin)
{
    const int t = threadIdx.x;
    const int lane = t & 63;
    const int wid  = t >> 6;
    const int bx = blockIdx.x;
    const int k  = bx >> 6;                 // 0..7
    const int rb = (bx & 63) * 4 + wid;     // 0..255 (32-row block)
    const int col  = lane & 15;
    const int quad = lane >> 4;
    const int dims = (quad & 1) * 8;
    const int part = quad >> 1;

    // A fragments for 2 groups of 16 rows
    f16x8 A[2];
    #pragma unroll
    for (int g = 0; g < 2; ++g) {
        const int row = rb * 32 + g * 16 + col;
        const float* xp = &xk[((size_t)k * NROWS + row) * DSUB + dims];
        f16x8 hi, lo;
        #pragma unroll
        for (int j = 0; j < 8; ++j) {
            const float s = xp[j] * 256.0f;      // pow2 scale keeps lo normal
            const _Float16 h = (_Float16)s;
            hi[j] = h;
            lo[j] = (_Float16)(s - (float)h);
        }
        A[g] = part ? lo : hi;
    }

    float m1[2][4], m2[2][4];
    int   idx[2][4];
    #pragma unroll
    for (int g = 0; g < 2; ++g)
        #pragma unroll
        for (int j = 0; j < 4; ++j) { m1[g][j] = 1e30f; m2[g][j] = 1e30f; idx[g][j] = 0; }

    const f16x8* b1p = &B1[((size_t)k * 256) * 64 + lane];
    const f16x8* b2p = &B2[((size_t)k * 256) * 64 + lane];
    const float* cnp = &cnorm[k * NC + col];

    #pragma unroll 2
    for (int tt = 0; tt < 256; ++tt) {
        const f16x8 b1 = b1p[tt * 64];
        const f16x8 b2 = b2p[tt * 64];
        const float nrm = cnp[tt * 16];
        f32x4 acc0 = {0.f, 0.f, 0.f, 0.f};
        f32x4 acc1 = {0.f, 0.f, 0.f, 0.f};
        acc0 = __builtin_amdgcn_mfma_f32_16x16x32_f16(A[0], b1, acc0, 0, 0, 0);
        acc0 = __builtin_amdgcn_mfma_f32_16x16x32_f16(A[0], b2, acc0, 0, 0, 0);
        acc1 = __builtin_amdgcn_mfma_f32_16x16x32_f16(A[1], b1, acc1, 0, 0, 0);
        acc1 = __builtin_amdgcn_mfma_f32_16x16x32_f16(A[1], b2, acc1, 0, 0, 0);
        const int c = tt * 16 + col;
        #pragma unroll
        for (int j = 0; j < 4; ++j) {
            {
                const float s = fmaf(acc0[j], DOTSCALE, nrm);
                const bool lt = s < m1[0][j];
                m2[0][j] = fminf(m2[0][j], fmaxf(m1[0][j], s));   // med3 idiom
                idx[0][j] = lt ? c : idx[0][j];
                m1[0][j] = fminf(s, m1[0][j]);
            }
            {
                const float s = fmaf(acc1[j], DOTSCALE, nrm);
                const bool lt = s < m1[1][j];
                m2[1][j] = fminf(m2[1][j], fmaxf(m1[1][j], s));
                idx[1][j] = lt ? c : idx[1][j];
                m1[1][j] = fminf(s, m1[1][j]);
            }
        }
    }

    // reduce across the 16 lanes of each quad (each quad holds rows quad*4+j, all cols)
    #pragma unroll
    for (int off = 1; off < 16; off <<= 1) {
        #pragma unroll
        for (int g = 0; g < 2; ++g)
            #pragma unroll
            for (int j = 0; j < 4; ++j) {
                const float om1 = __shfl_xor(m1[g][j], off, 64);
                const float om2 = __shfl_xor(m2[g][j], off, 64);
                const int  oidx = __shfl_xor(idx[g][j], off, 64);
                const bool better = (om1 < m1[g][j]) ||
                                    (om1 == m1[g][j] && oidx < idx[g][j]);
                m2[g][j] = fminf(fminf(m2[g][j], om2), fmaxf(m1[g][j], om1));
                m1[g][j] = better ? om1 : m1[g][j];
                idx[g][j] = better ? oidx : idx[g][j];
            }
    }

    if (col == 0) {
        #pragma unroll
        for (int g = 0; g < 2; ++g)
            #pragma unroll
            for (int j = 0; j < 4; ++j) {
                const int row = rb * 32 + g * 16 + quad * 4 + j;
                codes[row * KSUB + k] = idx[g][j];
                margin[row * KSUB + k] = m2[g][j] - m1[g][j];
            }
    }
}

// ---------------- Kernel 3: exact fp32 fallback for near-tied (row,k) ----------------
// one wave per (row,k); early-exits unless margin < FB_TAU. Exact math matches
// the round-1..5 passing fmaf-chain formula.
__global__ __launch_bounds__(256) void fallback_kernel(
    const float* __restrict__ xk, const float* __restrict__ ce,
    const float* __restrict__ cnorm, const float* __restrict__ margin,
    int* __restrict__ codes)
{
    const int wg = blockIdx.x * 4 + (threadIdx.x >> 6);  // 0..65535
    const int lane = threadIdx.x & 63;
    if (margin[wg] >= FB_TAU) return;                    // wave-uniform
    const int row = wg >> 3, k = wg & 7;

    float xr[DSUB];
    {
        const float* xp = &xk[((size_t)k * NROWS + row) * DSUB];
        #pragma unroll
        for (int q = 0; q < DSUB; q += 4) {
            const float4 v = *(const float4*)&xp[q];
            xr[q + 0] = -2.f * v.x; xr[q + 1] = -2.f * v.y;
            xr[q + 2] = -2.f * v.z; xr[q + 3] = -2.f * v.w;
        }
    }
    float m1 = 1e30f; int mi = NC;
    for (int c = lane; c < NC; c += 64) {
        const float* cp = &ce[((size_t)k * NC + c) * DSUB];
        float s = cnorm[k * NC + c];
        #pragma unroll
        for (int d = 0; d < DSUB; ++d) s = fmaf(xr[d], cp[d], s);
        if (s < m1) { m1 = s; mi = c; }   // strict < : lowest idx within lane
    }
    #pragma unroll
    for (int off = 1; off < 64; off <<= 1) {
        const float om1 = __shfl_xor(m1, off, 64);
        const int  omi = __shfl_xor(mi, off, 64);
        const bool better = (om1 < m1) || (om1 == m1 && omi < mi);
        m1 = better ? om1 : m1;
        mi = better ? omi : mi;
    }
    if (lane == 0) codes[wg] = mi;
}

// ---------------- Kernel 4: LUT gather + sum + bias -> llr ----------------
__global__ __launch_bounds__(256) void out_kernel(
    const float* __restrict__ centroids, const float* __restrict__ W3,
    const float* __restrict__ b3, const int* __restrict__ codes,
    float* __restrict__ out)
{
    const int gid = blockIdx.x * 256 + threadIdx.x;
    const int n = gid / OUTD;
    const int o = gid - n * OUTD;
    float acc = b3[o];
    #pragma unroll
    for (int k = 0; k < KSUB; ++k) {
        const int code = codes[n * KSUB + k];
        const float* cp = &centroids[((size_t)k * NC + code) * DSUB];
        const float* wp = &W3[(k * DSUB) * OUTD + o];
        #pragma unroll
        for (int d = 0; d < DSUB; ++d)
            acc = fmaf(cp[d], wp[d * OUTD], acc);
    }
    out[gid] = acc;
}

extern "C" void kernel_launch(void* const* d_in, const int* in_sizes, int n_in,
                              void* d_out, int out_size, void* d_ws, size_t ws_size,
                              hipStream_t stream)
{
    const float* z  = (const float*)d_in[0];
    const float* W1 = (const float*)d_in[1];
    const float* b1 = (const float*)d_in[2];
    const float* W2 = (const float*)d_in[3];
    const float* b2 = (const float*)d_in[4];
    const float* ce = (const float*)d_in[5];
    const float* W3 = (const float*)d_in[6];
    const float* b3 = (const float*)d_in[7];

    char* ws = (char*)d_ws;
    float* xk     = (float*)(ws + XK_OFF);
    float* cnorm  = (float*)(ws + CN_OFF);
    f16x8* B1     = (f16x8*)(ws + B1_OFF);
    f16x8* B2     = (f16x8*)(ws + B2_OFF);
    int*   codes  = (int*)  (ws + CO_OFF);
    float* margin = (float*)(ws + MG_OFF);

    hipLaunchKernelGGL(bprep_kernel, dim3(512), dim3(256), 0, stream, ce, B1, B2);
    hipLaunchKernelGGL(mlp_kernel, dim3(NROWS / 32), dim3(256), 0, stream,
                       z, W1, b1, W2, b2, ce, xk, cnorm);
    hipLaunchKernelGGL(argmin_kernel, dim3(512), dim3(256), 0, stream,
                       xk, B1, B2, cnorm, codes, margin);
    hipLaunchKernelGGL(fallback_kernel, dim3(NROWS * KSUB / 4), dim3(256), 0, stream,
                       xk, ce, cnorm, margin, codes);
    hipLaunchKernelGGL(out_kernel, dim3((NROWS * OUTD) / 256), dim3(256), 0, stream,
                       ce, W3, b3, codes, (float*)d_out);
}

// Round 7
// 194.732 us; speedup vs baseline: 1.3182x; 1.0710x over previous
//
#include <hip/hip_runtime.h>
#include <stdint.h>

#define NROWS 8192   // B*S
#define HDIM  128
#define KSUB  8
#define NC    4096
#define DSUB  16
#define OUTD  6

#define FB_TAU 4e-3f                // fallback margin; >> worst-case split-fp16 error (~1.4e-4)
#define DOTSCALE (-2.0f / 4096.0f)  // undo x*256, c*16 scaling; exact pow2

typedef _Float16 f16x8 __attribute__((ext_vector_type(8)));
typedef float    f32x4 __attribute__((ext_vector_type(4)));

// ws layout (bytes):
#define XK_OFF 0u            // xk:    [KSUB][NROWS][DSUB] fp32, 4 MiB
#define CN_OFF 4194304u      // cnorm: [KSUB][NC] fp32, 128 KiB
#define B1_OFF 4325376u      // B1:    [KSUB][256 tiles][64 lanes] f16x8, 2 MiB
#define PK_OFF 6422528u      // pk:    [2 splits][NROWS][KSUB] u64 (key<<32|idx), 1 MiB
#define M2_OFF 7471104u      // m2s:   [2 splits][NROWS][KSUB] fp32, 512 KiB
#define CO_OFF B1_OFF        // codes: [NROWS][KSUB] int, 256 KiB -- overlays B1 (dead after argmin)

// ---------------- Kernel 0: build fp16 hi/lo centroid B-fragments ----------------
// entry e = (k, tile, lane). quad<2 -> hi, quad>=2 -> lo (B2 = B1[lane^32]).
__global__ __launch_bounds__(256) void bprep_kernel(
    const float* __restrict__ ce, f16x8* __restrict__ B1)
{
    const int e = blockIdx.x * 256 + threadIdx.x;   // 0..131071
    const int k    = e >> 14;
    const int tile = (e >> 6) & 255;
    const int lane = e & 63;
    const int col  = lane & 15;
    const int quad = lane >> 4;
    const int dims = (quad & 1) * 8;
    const int part = quad >> 1;                      // 0: hi half of K, 1: lo half
    const int n = tile * 16 + col;
    const float* cp = &ce[((size_t)k * NC + n) * DSUB + dims];
    f16x8 hi, lo;
    #pragma unroll
    for (int j = 0; j < 8; ++j) {
        const float s = cp[j] * 16.0f;               // pow2 scale keeps lo normal
        const _Float16 h = (_Float16)s;
        hi[j] = h;
        lo[j] = (_Float16)(s - (float)h);
    }
    B1[e] = part ? lo : hi;
}

// ---------------- Kernel 1: MLP + centroid norms ----------------
__global__ __launch_bounds__(256) void mlp_kernel(
    const float* __restrict__ z, const float* __restrict__ W1, const float* __restrict__ b1,
    const float* __restrict__ W2, const float* __restrict__ b2,
    const float* __restrict__ centroids,
    float* __restrict__ xk, float* __restrict__ cnorm)
{
    __shared__ float h1s[32 * HDIM];    // 16 KiB
    __shared__ float w2s[HDIM * HDIM];  // 64 KiB
    const int t = threadIdx.x;
    const int row0 = blockIdx.x * 32;

    // centroid norms (blocks 0..127 cover KSUB*NC = 32768 centroids)
    if (blockIdx.x < (KSUB * NC) / 256) {
        const int g = blockIdx.x * 256 + t;
        const float4* cp = (const float4*)&centroids[(size_t)g * DSUB];
        float nn = 0.f;
        #pragma unroll
        for (int q = 0; q < 4; ++q) {
            const float4 v = cp[q];
            nn = fmaf(v.x, v.x, nn); nn = fmaf(v.y, v.y, nn);
            nn = fmaf(v.z, v.z, nn); nn = fmaf(v.w, v.w, nn);
        }
        cnorm[g] = nn;
    }

    // stage W2 (coalesced)
    {
        const float4* g4 = (const float4*)W2;
        float4* s4 = (float4*)w2s;
        #pragma unroll
        for (int q = 0; q < 16; ++q) s4[t + q * 256] = g4[t + q * 256];
    }

    // phase A: h1 = relu(z @ W1 + b1) into LDS (32x128)
    #pragma unroll
    for (int e = 0; e < 16; ++e) {
        const int idx = e * 256 + t;
        const int r = idx >> 7, j = idx & 127;
        const int n = row0 + r;
        float acc = b1[j];
        acc = fmaf(z[n * 3 + 0], W1[0 * HDIM + j], acc);
        acc = fmaf(z[n * 3 + 1], W1[1 * HDIM + j], acc);
        acc = fmaf(z[n * 3 + 2], W1[2 * HDIM + j], acc);
        h1s[idx] = fmaxf(acc, 0.f);
    }
    __syncthreads();

    // phase B: 4 rows x 4 cols per thread
    const int c4 = (t & 31) * 4;
    const int r4 = (t >> 5) * 4;
    float acc[4][4];
    #pragma unroll
    for (int a = 0; a < 4; ++a)
        #pragma unroll
        for (int b = 0; b < 4; ++b) acc[a][b] = 0.f;

    for (int k4 = 0; k4 < HDIM; k4 += 4) {
        float hh[4][4], ww[4][4];
        #pragma unroll
        for (int q = 0; q < 4; ++q) {
            const float4 v = *(const float4*)&h1s[(r4 + q) * HDIM + k4];
            hh[q][0] = v.x; hh[q][1] = v.y; hh[q][2] = v.z; hh[q][3] = v.w;
        }
        #pragma unroll
        for (int p = 0; p < 4; ++p) {
            const float4 v = *(const float4*)&w2s[(k4 + p) * HDIM + c4];
            ww[p][0] = v.x; ww[p][1] = v.y; ww[p][2] = v.z; ww[p][3] = v.w;
        }
        #pragma unroll
        for (int q = 0; q < 4; ++q)
            #pragma unroll
            for (int p = 0; p < 4; ++p) {
                acc[q][0] = fmaf(hh[q][p], ww[p][0], acc[q][0]);
                acc[q][1] = fmaf(hh[q][p], ww[p][1], acc[q][1]);
                acc[q][2] = fmaf(hh[q][p], ww[p][2], acc[q][2]);
                acc[q][3] = fmaf(hh[q][p], ww[p][3], acc[q][3]);
            }
    }

    const float4 bb = *(const float4*)&b2[c4];
    const int kk = c4 >> 4;
    const int dd = c4 & 15;
    #pragma unroll
    for (int q = 0; q < 4; ++q) {
        float4 o;
        o.x = fmaxf(acc[q][0] + bb.x, 0.f);
        o.y = fmaxf(acc[q][1] + bb.y, 0.f);
        o.z = fmaxf(acc[q][2] + bb.z, 0.f);
        o.w = fmaxf(acc[q][3] + bb.w, 0.f);
        *(float4*)&xk[((size_t)kk * NROWS + (row0 + r4 + q)) * DSUB + dd] = o;
    }
}

// ---------------- Kernel 2: MFMA argmin (latency-tuned) ----------------
// grid (64, 8 k, 2 csplit) = 1024 blocks -> 4 waves/SIMD. Each wave: 32 rows,
// 128 tiles. Independent MFMA accumulators (no chain), explicit prefetch of
// next tile's fragments, b2 = B1[lane^32]. Per-split (m1,m2,idx) -> ws.
__global__ __launch_bounds__(256, 4) void argmin_kernel(
    const float* __restrict__ xk, const f16x8* __restrict__ B1,
    const float* __restrict__ cnorm,
    unsigned long long* __restrict__ pk, float* __restrict__ m2s)
{
    const int t = threadIdx.x;
    const int lane = t & 63;
    const int wid  = t >> 6;
    const int k  = blockIdx.y;                 // 0..7
    const int cz = blockIdx.z;                 // 0..1
    const int rb = blockIdx.x * 4 + wid;       // 0..255 (32-row block)
    const int col  = lane & 15;
    const int quad = lane >> 4;
    const int dims = (quad & 1) * 8;
    const int part = quad >> 1;
    const int ct0 = cz * 128;                  // first tile of this split

    // A fragments for 2 groups of 16 rows
    f16x8 A[2];
    #pragma unroll
    for (int g = 0; g < 2; ++g) {
        const int row = rb * 32 + g * 16 + col;
        const float* xp = &xk[((size_t)k * NROWS + row) * DSUB + dims];
        f16x8 hi, lo;
        #pragma unroll
        for (int j = 0; j < 8; ++j) {
            const float s = xp[j] * 256.0f;      // pow2 scale keeps lo normal
            const _Float16 h = (_Float16)s;
            hi[j] = h;
            lo[j] = (_Float16)(s - (float)h);
        }
        A[g] = part ? lo : hi;
    }

    float m1[2][4], m2[2][4];
    int   idx[2][4];
    #pragma unroll
    for (int g = 0; g < 2; ++g)
        #pragma unroll
        for (int j = 0; j < 4; ++j) { m1[g][j] = 1e30f; m2[g][j] = 1e30f; idx[g][j] = 0; }

    const f16x8* bp = &B1[((size_t)k * 256 + ct0) * 64];
    const float* cnp = &cnorm[k * NC + ct0 * 16 + col];
    const int l2 = lane ^ 32;                  // B2 fragment = B1 with part flipped

    f16x8 cb1 = bp[lane], cb2 = bp[l2];
    float cnv = cnp[0];

    for (int tt = 0; tt < 128; ++tt) {
        const f16x8 b1 = cb1, b2 = cb2;
        const float nrm = cnv;
        if (tt + 1 < 128) {                    // prefetch next tile
            cb1 = bp[(tt + 1) * 64 + lane];
            cb2 = bp[(tt + 1) * 64 + l2];
            cnv = cnp[(tt + 1) * 16];
        }
        f32x4 z4 = {0.f, 0.f, 0.f, 0.f};
        f32x4 a0a = __builtin_amdgcn_mfma_f32_16x16x32_f16(A[0], b1, z4, 0, 0, 0);
        f32x4 a0b = __builtin_amdgcn_mfma_f32_16x16x32_f16(A[0], b2, z4, 0, 0, 0);
        f32x4 a1a = __builtin_amdgcn_mfma_f32_16x16x32_f16(A[1], b1, z4, 0, 0, 0);
        f32x4 a1b = __builtin_amdgcn_mfma_f32_16x16x32_f16(A[1], b2, z4, 0, 0, 0);
        const int c = (ct0 + tt) * 16 + col;
        #pragma unroll
        for (int j = 0; j < 4; ++j) {
            {
                const float s = fmaf(a0a[j] + a0b[j], DOTSCALE, nrm);
                const bool lt = s < m1[0][j];
                m2[0][j] = __builtin_amdgcn_fmed3f(s, m1[0][j], m2[0][j]);
                idx[0][j] = lt ? c : idx[0][j];
                m1[0][j] = fminf(s, m1[0][j]);
            }
            {
                const float s = fmaf(a1a[j] + a1b[j], DOTSCALE, nrm);
                const bool lt = s < m1[1][j];
                m2[1][j] = __builtin_amdgcn_fmed3f(s, m1[1][j], m2[1][j]);
                idx[1][j] = lt ? c : idx[1][j];
                m1[1][j] = fminf(s, m1[1][j]);
            }
        }
    }

    // reduce across the 16 lanes of each quad
    #pragma unroll
    for (int off = 1; off < 16; off <<= 1) {
        #pragma unroll
        for (int g = 0; g < 2; ++g)
            #pragma unroll
            for (int j = 0; j < 4; ++j) {
                const float om1 = __shfl_xor(m1[g][j], off, 64);
                const float om2 = __shfl_xor(m2[g][j], off, 64);
                const int  oidx = __shfl_xor(idx[g][j], off, 64);
                const bool better = (om1 < m1[g][j]) ||
                                    (om1 == m1[g][j] && oidx < idx[g][j]);
                m2[g][j] = fminf(fminf(m2[g][j], om2), fmaxf(m1[g][j], om1));
                m1[g][j] = better ? om1 : m1[g][j];
                idx[g][j] = better ? oidx : idx[g][j];
            }
    }

    if (col == 0) {
        #pragma unroll
        for (int g = 0; g < 2; ++g)
            #pragma unroll
            for (int j = 0; j < 4; ++j) {
                const int row = rb * 32 + g * 16 + quad * 4 + j;
                unsigned u = __float_as_uint(m1[g][j]);
                u = (u & 0x80000000u) ? ~u : (u | 0x80000000u);  // order-preserving
                pk [((size_t)cz * NROWS + row) * KSUB + k] =
                    ((unsigned long long)u << 32) | (unsigned)idx[g][j];
                m2s[((size_t)cz * NROWS + row) * KSUB + k] = m2[g][j];
            }
    }
}

// ---------------- Kernel 3: merge splits + exact fp32 fallback ----------------
// one wave per (row,k). Merges the 2 centroid-splits exactly
// (m2 = min(m2a, m2b, m1_loser)); rescans in fp32 only if margin < FB_TAU.
__global__ __launch_bounds__(256) void fallback_kernel(
    const float* __restrict__ xk, const float* __restrict__ ce,
    const float* __restrict__ cnorm, const unsigned long long* __restrict__ pk,
    const float* __restrict__ m2s, int* __restrict__ codes)
{
    const int wg = blockIdx.x * 4 + (threadIdx.x >> 6);  // 0..65535
    const int lane = threadIdx.x & 63;

    const unsigned long long a = pk[wg];
    const unsigned long long b = pk[(size_t)NROWS * KSUB + wg];
    const unsigned long long w = a < b ? a : b;          // winner (ties -> lower idx)
    const unsigned long long l = a < b ? b : a;
    const unsigned uw = (unsigned)(w >> 32), ul = (unsigned)(l >> 32);
    const float m1  = __uint_as_float((uw & 0x80000000u) ? (uw ^ 0x80000000u) : ~uw);
    const float m1l = __uint_as_float((ul & 0x80000000u) ? (ul ^ 0x80000000u) : ~ul);
    const float m2 = fminf(fminf(m2s[wg], m2s[(size_t)NROWS * KSUB + wg]), m1l);

    if (m2 - m1 >= FB_TAU) {
        if (lane == 0) codes[wg] = (int)(w & 0xFFFFFFFFull);
        return;
    }

    const int row = wg >> 3, k = wg & 7;
    float xr[DSUB];
    {
        const float* xp = &xk[((size_t)k * NROWS + row) * DSUB];
        #pragma unroll
        for (int q = 0; q < DSUB; q += 4) {
            const float4 v = *(const float4*)&xp[q];
            xr[q + 0] = -2.f * v.x; xr[q + 1] = -2.f * v.y;
            xr[q + 2] = -2.f * v.z; xr[q + 3] = -2.f * v.w;
        }
    }
    float bm = 1e30f; int bi = NC;
    for (int c = lane; c < NC; c += 64) {
        const float* cp = &ce[((size_t)k * NC + c) * DSUB];
        float s = cnorm[k * NC + c];
        #pragma unroll
        for (int d = 0; d < DSUB; ++d) s = fmaf(xr[d], cp[d], s);
        if (s < bm) { bm = s; bi = c; }
    }
    #pragma unroll
    for (int off = 1; off < 64; off <<= 1) {
        const float om = __shfl_xor(bm, off, 64);
        const int  oi = __shfl_xor(bi, off, 64);
        const bool better = (om < bm) || (om == bm && oi < bi);
        bm = better ? om : bm;
        bi = better ? oi : bi;
    }
    if (lane == 0) codes[wg] = bi;
}

// ---------------- Kernel 4: LUT gather + sum + bias -> llr ----------------
__global__ __launch_bounds__(256) void out_kernel(
    const float* __restrict__ centroids, const float* __restrict__ W3,
    const float* __restrict__ b3, const int* __restrict__ codes,
    float* __restrict__ out)
{
    const int gid = blockIdx.x * 256 + threadIdx.x;
    const int n = gid / OUTD;
    const int o = gid - n * OUTD;
    float acc = b3[o];
    #pragma unroll
    for (int k = 0; k < KSUB; ++k) {
        const int code = codes[n * KSUB + k];
        const float* cp = &centroids[((size_t)k * NC + code) * DSUB];
        const float* wp = &W3[(k * DSUB) * OUTD + o];
        #pragma unroll
        for (int d = 0; d < DSUB; ++d)
            acc = fmaf(cp[d], wp[d * OUTD], acc);
    }
    out[gid] = acc;
}

extern "C" void kernel_launch(void* const* d_in, const int* in_sizes, int n_in,
                              void* d_out, int out_size, void* d_ws, size_t ws_size,
                              hipStream_t stream)
{
    const float* z  = (const float*)d_in[0];
    const float* W1 = (const float*)d_in[1];
    const float* b1 = (const float*)d_in[2];
    const float* W2 = (const float*)d_in[3];
    const float* b2 = (const float*)d_in[4];
    const float* ce = (const float*)d_in[5];
    const float* W3 = (const float*)d_in[6];
    const float* b3 = (const float*)d_in[7];

    char* ws = (char*)d_ws;
    float* xk     = (float*)(ws + XK_OFF);
    float* cnorm  = (float*)(ws + CN_OFF);
    f16x8* B1     = (f16x8*)(ws + B1_OFF);
    unsigned long long* pk = (unsigned long long*)(ws + PK_OFF);
    float* m2s    = (float*)(ws + M2_OFF);
    int*   codes  = (int*)  (ws + CO_OFF);   // overlays B1 (dead after argmin)

    hipLaunchKernelGGL(bprep_kernel, dim3(512), dim3(256), 0, stream, ce, B1);
    hipLaunchKernelGGL(mlp_kernel, dim3(NROWS / 32), dim3(256), 0, stream,
                       z, W1, b1, W2, b2, ce, xk, cnorm);
    hipLaunchKernelGGL(argmin_kernel, dim3(64, 8, 2), dim3(256), 0, stream,
                       xk, B1, cnorm, pk, m2s);
    hipLaunchKernelGGL(fallback_kernel, dim3(NROWS * KSUB / 4), dim3(256), 0, stream,
                       xk, ce, cnorm, pk, m2s, codes);
    hipLaunchKernelGGL(out_kernel, dim3((NROWS * OUTD) / 256), dim3(256), 0, stream,
                       ce, W3, b3, codes, (float*)d_out);
}